// Round 9
// baseline (142.242 us; speedup 1.0000x reference)
//
#include <hip/hip_runtime.h>
#include <hip/hip_bf16.h>
#include <math.h>

// MPDO contraction via delta-decomposed bf16 MFMA.
// Per site: E' = 2E + sum_k [ a_k^T E + E b_k + a_k^T (E b_k) ],  a,b = middle - I (O(0.01))
// 2E term carried in fp32 C-layout registers; corrections via v_mfma_f32_32x32x16_bf16.
// One wave per batch element, 4 waves/block, grid = B/4.
//
// r7 fix: output format. Harness compares out_size(=B) float32 slots against the
// complex64 ref elementwise (imag(ref)=0 since rho>0) -> write out[b] = log|rho_b|
// real-only. Previous interleaved (re,im) writes put 0 on odd slots (err 51.5 = |ref|max)
// and ran OOB past the 8 KB buffer.
//
// Frag layouts (desk-validated r4/r5 against m214's verified cvt_pk+permlane recipe):
//   A/B input: elem e of lane l <-> k = 8*(l>>5) + e   (per 16-K MFMA call)
//   C/D:       col = lane&31, row = (r&3) + 8*(r>>2) + 4*(lane>>5)   [m74/m101]

typedef __attribute__((ext_vector_type(8)))  short short8;   // 8 bf16 = 4 VGPR (MFMA A/B frag)
typedef __attribute__((ext_vector_type(16))) float f32x16;   // MFMA C/D frag

#define EPITCH 33   // E LDS pitch: (row*33+col)%32 and (col*33+c)%32 are permutations ->
                    // writes/reads at worst 2-way (free, m136); 132B pitch blocks b128 forming.

static __device__ inline unsigned pk2(float lo, float hi) {
    union { __hip_bfloat162 h; unsigned u; } cv;
    cv.h = __float22bfloat162_rn(make_float2(lo, hi));       // v_cvt_pk_bf16_f32
    return cv.u;
}
static __device__ inline short8 mk8(unsigned u0, unsigned u1, unsigned u2, unsigned u3) {
    union { short8 v; unsigned u[4]; } r;
    r.u[0] = u0; r.u[1] = u1; r.u[2] = u2; r.u[3] = u3;
    return r.v;
}
static __device__ inline void pl32swap(unsigned& x, unsigned& y) {
    // after: x = {x.lanes0-31, y.lanes0-31}, y = {x.lanes32-63, y.lanes32-63}
    asm("v_permlane32_swap_b32 %0, %1" : "+v"(x), "+v"(y));
}
static __device__ inline f32x16 MFMA(short8 a, short8 b, f32x16 c) {
    return __builtin_amdgcn_mfma_f32_32x32x16_bf16(a, b, c, 0, 0, 0);
}
static __device__ inline f32x16 zero16() {
    f32x16 z = {0.f,0.f,0.f,0.f,0.f,0.f,0.f,0.f,0.f,0.f,0.f,0.f,0.f,0.f,0.f,0.f};
    return z;
}

__global__ __launch_bounds__(256, 2) void mpdo_mfma(
    const int*   __restrict__ qn,
    const float* __restrict__ left,
    const float* __restrict__ right,
    const float* __restrict__ middle,
    float*       __restrict__ out,
    const int    cplx)                 // 0: out[b]=re only; 1: out[2b]=re, out[2b+1]=im
{
    // mid_b: bf16-packed, identity-subtracted site tensor (shared by the 4 waves;
    // per-wave sr/sc select rows).  mid_b[((s*2+k)*16+p)*32+j] = pk2(a[2p][j], a[2p+1][j])
    __shared__ unsigned mid_b[2048];              // 8 KB
    __shared__ float    E_s[4][32*EPITCH];        // 16.5 KB, per-wave f32 edge (A-op frags)

    const int t    = threadIdx.x;
    const int w    = t >> 6;
    const int lane = t & 63;
    const int hi   = lane >> 5;
    const int col  = lane & 31;
    const int elem = blockIdx.x * 4 + w;
    const int* q   = qn + (size_t)elem * 128;
    float* Ew = E_s[w];

    // staging decomposition: thread handles row-pair sp, column-pair sj, for s=0,1
    const int sp = (t >> 4) & 15;
    const int sj = t & 15;
    const int jj = sj * 2;                        // even column j
    const float dj = (sp == sj) ? 1.0f : 0.0f;    // identity hits (2sp,jj) and (2sp+1,jj+1)
    const int v0 = (0 + 2*sp) * 16 + sj;          // float4 index, s=0  (v+16 = row i+1)
    const int v1 = (32 + 2*sp) * 16 + sj;         // s=1

    // C-layout rows per accumulator register (m74/m101 measured mapping)
    int rowr[16];
    #pragma unroll
    for (int r = 0; r < 16; ++r) rowr[r] = (r & 3) + 8*(r >> 2) + 4*hi;

    // ---- init edge E[a][m] = sum_x L[qr0][a][x] L[qc0][m][x]  (fp32, C-layout regs) ----
    float e[16];
    {
        const float* Lr = left + (size_t)q[0]  * 64;
        const float* Lc = left + (size_t)q[64] * 64;
        const float c0v = Lc[col*2 + 0], c1v = Lc[col*2 + 1];
        #pragma unroll
        for (int r = 0; r < 16; ++r)
            e[r] = Lr[rowr[r]*2 + 0] * c0v + Lr[rowr[r]*2 + 1] * c1v;
    }

    // ---- prefetch site 1 middle tile + quantum numbers ----
    const float4* gm = (const float4*)middle;
    float4 A0 = gm[v0], A1 = gm[v0 + 16], B0 = gm[v1], B1 = gm[v1 + 16];
    int srn = q[1], scn = q[65];

    for (int site = 1; site <= 62; ++site) {
        // -- transform prefetched tile -> mid_b (bf16 pairs, delta-subtracted) --
        {
            uint2* m2 = (uint2*)mid_b;
            // s=0, k=0 / k=1   (float4 lanes: .x=(j,k=0) .y=(j,1) .z=(j+1,0) .w=(j+1,1))
            m2[((0*16 + sp)*32 + jj) >> 1] = make_uint2(pk2(A0.x - dj, A1.x), pk2(A0.z, A1.z - dj));
            m2[((1*16 + sp)*32 + jj) >> 1] = make_uint2(pk2(A0.y - dj, A1.y), pk2(A0.w, A1.w - dj));
            // s=1, k=0 / k=1
            m2[((2*16 + sp)*32 + jj) >> 1] = make_uint2(pk2(B0.x - dj, B1.x), pk2(B0.z, B1.z - dj));
            m2[((3*16 + sp)*32 + jj) >> 1] = make_uint2(pk2(B0.y - dj, B1.y), pk2(B0.w, B1.w - dj));
        }
        // -- write current edge to LDS (for E-as-A-operand frags); conflict-free --
        #pragma unroll
        for (int r = 0; r < 16; ++r) Ew[rowr[r]*EPITCH + col] = e[r];
        __syncthreads();

        const int sr = srn, sc = scn;
        // -- prefetch next site (A0..B1 already consumed by staging above) --
        if (site < 62) {
            const float4* gn = (const float4*)(middle + (size_t)site * 4096);
            A0 = gn[v0]; A1 = gn[v0 + 16]; B0 = gn[v1]; B1 = gn[v1 + 16];
            srn = q[site + 1]; scn = q[site + 65];
        }

        // -- a^T and b fragments: 4 raw b32 reads each, already bf16+delta --
        short8 aT[2][2], bF[2][2];
        #pragma unroll
        for (int k = 0; k < 2; ++k) {
            #pragma unroll
            for (int h = 0; h < 2; ++h) {
                const int pa = ((sr*2 + k)*16 + 8*h + 4*hi) * 32 + col;
                aT[k][h] = mk8(mid_b[pa], mid_b[pa+32], mid_b[pa+64], mid_b[pa+96]);
                const int pb = ((sc*2 + k)*16 + 8*h + 4*hi) * 32 + col;
                bF[k][h] = mk8(mid_b[pb], mid_b[pb+32], mid_b[pb+64], mid_b[pb+96]);
            }
        }
        // -- E as A-operand: EA[h] elem e = E[col][16h+8hi+e]; conflict-free b32 reads --
        short8 EA[2];
        #pragma unroll
        for (int h = 0; h < 2; ++h) {
            const int base = col*EPITCH + 16*h + 8*hi;
            const float f0 = Ew[base+0], f1 = Ew[base+1], f2 = Ew[base+2], f3 = Ew[base+3];
            const float f4 = Ew[base+4], f5 = Ew[base+5], f6 = Ew[base+6], f7 = Ew[base+7];
            EA[h] = mk8(pk2(f0,f1), pk2(f2,f3), pk2(f4,f5), pk2(f6,f7));
        }
        // -- E as B-operand: EB[h] elem e = E[16h+8hi+e][col], via permlane32_swap --
        short8 EB[2];
        #pragma unroll
        for (int h = 0; h < 2; ++h) {
            unsigned ua = pk2(e[8*h+0], e[8*h+1]);   // rows 16h+4hi+{0,1}
            unsigned ub = pk2(e[8*h+2], e[8*h+3]);   // rows 16h+4hi+{2,3}
            unsigned uc = pk2(e[8*h+4], e[8*h+5]);   // rows 16h+8+4hi+{0,1}
            unsigned ud = pk2(e[8*h+6], e[8*h+7]);   // rows 16h+8+4hi+{2,3}
            pl32swap(ua, uc); pl32swap(ub, ud);      // -> frag words 0/2 and 1/3
            EB[h] = mk8(ua, ub, uc, ud);
        }

        // -- V_k = E b_k --
        f32x16 V0 = MFMA(EA[0], bF[0][0], zero16());
        V0 = MFMA(EA[1], bF[0][1], V0);
        f32x16 V1 = MFMA(EA[0], bF[1][0], zero16());
        V1 = MFMA(EA[1], bF[1][1], V1);
        // -- acc = sum_k a_k^T E --
        f32x16 acc = MFMA(aT[0][0], EB[0], zero16());
        acc = MFMA(aT[0][1], EB[1], acc);
        acc = MFMA(aT[1][0], EB[0], acc);
        acc = MFMA(aT[1][1], EB[1], acc);
        // -- acc += a_k^T V_k  (V B-frags from V regs via permlane, same map as EB) --
        #pragma unroll
        for (int k = 0; k < 2; ++k) {
            const f32x16& V = k ? V1 : V0;
            #pragma unroll
            for (int h = 0; h < 2; ++h) {
                unsigned ua = pk2(V[8*h+0], V[8*h+1]);
                unsigned ub = pk2(V[8*h+2], V[8*h+3]);
                unsigned uc = pk2(V[8*h+4], V[8*h+5]);
                unsigned ud = pk2(V[8*h+6], V[8*h+7]);
                pl32swap(ua, uc); pl32swap(ub, ud);
                acc = MFMA(aT[k][h], mk8(ua, ub, uc, ud), acc);
            }
        }
        // -- E' = 2E + acc + V0 + V1  (fp32) --
        #pragma unroll
        for (int r = 0; r < 16; ++r)
            e[r] = 2.0f*e[r] + acc[r] + V0[r] + V1[r];
        __syncthreads();
    }

    // ---- epilogue: rho = sum E[a][m]*RE[a][m];  out = log(rho) ----
    {
        const float* Rr = right + (size_t)q[63]  * 64;
        const float* Rc = right + (size_t)q[127] * 64;
        const float rc0 = Rc[col*2 + 0], rc1 = Rc[col*2 + 1];
        float part = 0.f;
        #pragma unroll
        for (int r = 0; r < 16; ++r) {
            const float re = Rr[rowr[r]*2 + 0]*rc0 + Rr[rowr[r]*2 + 1]*rc1;
            part += e[r] * re;
        }
        #pragma unroll
        for (int off = 32; off > 0; off >>= 1)
            part += __shfl_down(part, off, 64);
        if (lane == 0) {
            const float re = logf(fabsf(part));
            if (cplx) {
                out[2*elem + 0] = re;
                out[2*elem + 1] = (part < 0.f) ? 3.14159265358979323846f : 0.f;
            } else {
                out[elem] = re;   // harness compares B float32 slots vs complex ref (imag=0)
            }
        }
    }
}

extern "C" void kernel_launch(void* const* d_in, const int* in_sizes, int n_in,
                              void* d_out, int out_size, void* d_ws, size_t ws_size,
                              hipStream_t stream) {
    const int*   qn     = (const int*)  d_in[0];
    const float* left   = (const float*)d_in[1];
    const float* right  = (const float*)d_in[2];
    const float* middle = (const float*)d_in[3];
    float* out = (float*)d_out;

    const int B    = in_sizes[0] / 128;        // qn is [B, 2L], 2L = 128
    const int cplx = (out_size >= 2 * B) ? 1 : 0;
    mpdo_mfma<<<B / 4, 256, 0, stream>>>(qn, left, right, middle, out, cplx);
}